// Round 11
// baseline (151.787 us; speedup 1.0000x reference)
//
#include <hip/hip_runtime.h>
#include <math.h>

#define NTOK 8192
#define NEMB 8192
#define DIM  256

typedef _Float16 f16x8 __attribute__((ext_vector_type(8)));   // 4 VGPRs
typedef _Float16 f16x4 __attribute__((ext_vector_type(4)));
typedef float    f32x4 __attribute__((ext_vector_type(4)));

// ---------------------------------------------------------------------------
// Kernel A: cast X and C to fp16 (RNE); fused exact fp32 ||c||^2 and ||x||^2
// (each wave covers exactly one 256-elem row: 64 lanes x 4 floats). C-branch
// blocks x<8 zero counts, block x==8 zeros done[]; X-branch blocks x<8 init
// keys to u64-max.
__global__ __launch_bounds__(256) void convert_kernel(
        const float* __restrict__ X, const float* __restrict__ C,
        _Float16* __restrict__ Xh, _Float16* __restrict__ Ch,
        float* __restrict__ cnorm, float* __restrict__ xnorm,
        unsigned long long* __restrict__ keys, int* __restrict__ counts,
        int* __restrict__ done) {
    const bool isC = (blockIdx.y != 0);
    if (isC && blockIdx.x < 8) {
        ((int4*)counts)[blockIdx.x * 256 + threadIdx.x] = make_int4(0, 0, 0, 0);
    }
    if (isC && blockIdx.x == 8 && threadIdx.x < 64) done[threadIdx.x] = 0;
    if (!isC && blockIdx.x < 8) {
        int4 ff = make_int4(-1, -1, -1, -1);
        ((int4*)keys)[blockIdx.x * 512 + threadIdx.x * 2]     = ff;
        ((int4*)keys)[blockIdx.x * 512 + threadIdx.x * 2 + 1] = ff;
    }
    const float* src = isC ? C : X;
    _Float16* dst = isC ? Ch : Xh;
    size_t t = (size_t)blockIdx.x * 256 + threadIdx.x;   // one float4 per thread
    float4 x = *(const float4*)&src[t * 4];
    f16x4 h;
    h[0] = (_Float16)x.x; h[1] = (_Float16)x.y;
    h[2] = (_Float16)x.z; h[3] = (_Float16)x.w;
    *(f16x4*)&dst[t * 4] = h;
    float s = x.x * x.x + x.y * x.y + x.z * x.z + x.w * x.w;
    #pragma unroll
    for (int off = 32; off >= 1; off >>= 1) s += __shfl_xor(s, off);
    if ((threadIdx.x & 63) == 0) {
        if (isC) cnorm[t >> 6] = s; else xnorm[t >> 6] = s;
    }
}

// ---------------------------------------------------------------------------
// Stage one 128x64 fp16 tile pair (A=codes, B=tokens) into LDS via
// global_load_lds width-16. 16B granules XOR-swizzled by (row&7): frag
// ds_read_b128 <=2-way (free), staging lane-contiguous.
__device__ __forceinline__ void stage_pair(
        const _Float16* __restrict__ Ag, const _Float16* __restrict__ Bg,
        _Float16* Abase, _Float16* Bbase, int t) {
    #pragma unroll
    for (int c = 0; c < 4; ++c) {
        int gr  = c * 256 + t;                   // granule 0..1023
        int row = gr >> 3;
        int kg  = (gr & 7) ^ (row & 7);          // un-swizzle for global
        __builtin_amdgcn_global_load_lds(
            (const __attribute__((address_space(1))) void*)(Ag + (size_t)row * DIM + kg * 8),
            (__attribute__((address_space(3))) void*)(Abase + (size_t)gr * 8), 16, 0, 0);
        __builtin_amdgcn_global_load_lds(
            (const __attribute__((address_space(1))) void*)(Bg + (size_t)row * DIM + kg * 8),
            (__attribute__((address_space(3))) void*)(Bbase + (size_t)gr * 8), 16, 0, 0);
    }
}

__device__ __forceinline__ void compute_pair(
        const _Float16* Abase, const _Float16* Bbase,
        f32x4 (&acc)[4][4], int wm, int wn, int lrow, int g) {
    #pragma unroll
    for (int ks = 0; ks < 2; ++ks) {
        const int kg = ks * 4 + g;
        f16x8 af[4], bf_[4];
        #pragma unroll
        for (int tm = 0; tm < 4; ++tm) {
            int row = wm + tm * 16 + lrow;
            af[tm] = *(const f16x8*)&Abase[(row * 8 + (kg ^ (row & 7))) * 8];
        }
        #pragma unroll
        for (int tn = 0; tn < 4; ++tn) {
            int row = wn + tn * 16 + lrow;
            bf_[tn] = *(const f16x8*)&Bbase[(row * 8 + (kg ^ (row & 7))) * 8];
        }
        #pragma unroll
        for (int tm = 0; tm < 4; ++tm)
            #pragma unroll
            for (int tn = 0; tn < 4; ++tn)
                acc[tm][tn] = __builtin_amdgcn_mfma_f32_16x16x32_f16(
                    af[tm], bf_[tn], acc[tm][tn], 0, 0, 0);
    }
}

// ---------------------------------------------------------------------------
// Kernel B: fp16 distance GEMM (K=256, fp32 accum), A=codes, single-barrier
// dbuf staging, argmin -> packed u64 atomicMin into keys[] (bits(d+64)<<32 |
// code: order-isomorphic, tie -> lower code, order-independent => replay-
// safe). FUSED GATHER: per token tile, the 64th (last-arriving) block unpacks
// the final keys (non-mutating RMW read), gathers C rows -> out, histograms,
// and stores the loss partial. Fence-free: __syncthreads() drains vmcnt(0),
// so this block's atomicMins completed at the coherent point before the done-
// counter increment; keys/counts flow only through device-scope atomics
// (r8 post-mortem: threadfence + idle-GPU finalize cost +26us — avoided).
__global__ __launch_bounds__(256) void mfma_argmin_kernel(
        const _Float16* __restrict__ Xh, const _Float16* __restrict__ Ch,
        const float* __restrict__ cnorm, unsigned long long* __restrict__ keys,
        const float* __restrict__ C, const float* __restrict__ xnorm,
        int* __restrict__ counts, float* __restrict__ out,
        float* __restrict__ psum, int* __restrict__ done) {
    __shared__ __align__(16) _Float16 lds[32768];   // 64 KB: buf0, buf1
    __shared__ int last;

    const int t = threadIdx.x;
    const int wid = t >> 6, lane = t & 63;
    const int tb0 = blockIdx.x * 128;   // token block
    const int cb0 = blockIdx.y * 128;   // code block
    const int wm = (wid >> 1) * 64;     // wave's code offset
    const int wn = (wid & 1) * 64;      // wave's token offset
    const int lrow = lane & 15;
    const int g = lane >> 4;            // quad

    f32x4 acc[4][4];                    // [tm=codes][tn=tokens]
    #pragma unroll
    for (int a = 0; a < 4; ++a)
        #pragma unroll
        for (int b = 0; b < 4; ++b) acc[a][b] = (f32x4)0.0f;

    const _Float16* Ag = Ch + (size_t)cb0 * DIM;   // codes
    const _Float16* Bg = Xh + (size_t)tb0 * DIM;   // tokens

    stage_pair(Ag, Bg, lds, lds + 8192, t);        // phase 0 -> buf0
    __syncthreads();
    #pragma unroll
    for (int p = 0; p < 4; ++p) {
        _Float16* cur = lds + (p & 1) * 16384;
        if (p < 3) {
            _Float16* nxt = lds + ((p + 1) & 1) * 16384;
            stage_pair(Ag + (p + 1) * 64, Bg + (p + 1) * 64, nxt, nxt + 8192, t);
        }
        compute_pair(cur, cur + 8192, acc, wm, wn, lrow, g);
        __syncthreads();
    }

    // ---- epilogue: d = ||c||^2 - 2 c.x ; argmin over this block's 128 codes
    float* cn_lds = (float*)lds;                   // [128]
    float* cmb_v  = (float*)lds + 128;             // [128][2]
    int*   cmb_i  = (int*)((float*)lds + 384);     // [128][2]
    if (t < 128) cn_lds[t] = cnorm[cb0 + t];
    __syncthreads();

    float cn[16];
    #pragma unroll
    for (int tm = 0; tm < 4; ++tm)
        #pragma unroll
        for (int reg = 0; reg < 4; ++reg)
            cn[tm * 4 + reg] = cn_lds[wm + tm * 16 + g * 4 + reg];

    #pragma unroll
    for (int tn = 0; tn < 4; ++tn) {
        float bv = 1e30f; int bi = 0x7fffffff;
        #pragma unroll
        for (int tm = 0; tm < 4; ++tm) {
            #pragma unroll
            for (int reg = 0; reg < 4; ++reg) {
                float d = fmaf(-2.0f, acc[tm][tn][reg], cn[tm * 4 + reg]);
                int code = cb0 + wm + tm * 16 + g * 4 + reg;  // ascending -> strict <
                if (d < bv) { bv = d; bi = code; }
            }
        }
        #pragma unroll
        for (int off = 16; off <= 32; off <<= 1) {  // reduce over the 4 quads
            float ov = __shfl_xor(bv, off);
            int   oi = __shfl_xor(bi, off);
            if (ov < bv || (ov == bv && oi < bi)) { bv = ov; bi = oi; }
        }
        if (g == 0) {
            int tl = wn + tn * 16 + lrow;           // token-local 0..127
            cmb_v[tl * 2 + (wid >> 1)] = bv;
            cmb_i[tl * 2 + (wid >> 1)] = bi;
        }
    }
    __syncthreads();
    if (t < 128) {
        float v0 = cmb_v[t * 2], v1 = cmb_v[t * 2 + 1];
        int   i0 = cmb_i[t * 2], i1 = cmb_i[t * 2 + 1];
        bool tk = (v1 < v0) || (v1 == v0 && i1 < i0);
        float bv = tk ? v1 : v0;
        int   bi = tk ? i1 : i0;
        unsigned long long key =
            ((unsigned long long)__builtin_bit_cast(unsigned, bv + 64.0f) << 32)
            | (unsigned)bi;
        atomicMin(&keys[tb0 + t], key);
    }

    // ---- fused gather: last-arriving block for this token tile ------------
    __syncthreads();    // compiler emits s_waitcnt vmcnt(0): atomicMins done
    if (t == 0) last = (atomicAdd(&done[blockIdx.x], 1) == 63);
    __syncthreads();
    if (!last) return;

    int*   idx_lds = (int*)lds;                          // [128]
    float* wsum    = (float*)((char*)lds + 512);         // [2]
    if (t < 128) {
        unsigned long long k = atomicMin(&keys[tb0 + t], ~0ull);  // RMW read
        int bi  = (int)(unsigned)k;
        float d = __builtin_bit_cast(float, (unsigned)(k >> 32)) - 64.0f;
        idx_lds[t] = bi;
        atomicAdd(&counts[bi], 1);
        float lt = d + xnorm[tb0 + t];               // ||x - c||^2 this token
        #pragma unroll
        for (int off = 32; off >= 1; off >>= 1) lt += __shfl_xor(lt, off);
        if (lane == 0) wsum[wid] = lt;
    }
    __syncthreads();
    if (t == 0) psum[blockIdx.x] = wsum[0] + wsum[1];
    #pragma unroll 1
    for (int r = 0; r < 32; ++r) {
        int token = tb0 + wid * 32 + r;
        int e = idx_lds[wid * 32 + r];
        float4 q = *(const float4*)&C[(size_t)e * DIM + lane * 4];
        *(float4*)&out[(size_t)token * DIM + lane * 4] = q;
    }
}

// ---------------------------------------------------------------------------
// Kernel C: entropy over the 8192-bin histogram + loss. Single small block,
// plain loads (visibility via kernel boundary).
__global__ __launch_bounds__(256) void finalize_kernel(
        const int* __restrict__ counts, const float* __restrict__ psum,
        float* __restrict__ out) {
    const int t = threadIdx.x;
    double local = 0.0;
    #pragma unroll 1
    for (int e = t; e < NEMB; e += 256) {
        float p = (float)counts[e] * (1.0f / (float)NTOK);
        local += (double)(p * logf(p + 1e-10f));
    }
    float ls = (t < 64) ? psum[t] : 0.0f;        // 64 token-tile partials
    #pragma unroll
    for (int off = 32; off >= 1; off >>= 1) {
        local += __shfl_xor(local, off);
        ls    += __shfl_xor(ls, off);
    }
    __shared__ double she[4];
    __shared__ float  shs[4];
    int lane = t & 63, wid = t >> 6;
    if (lane == 0) { she[wid] = local; shs[wid] = ls; }
    __syncthreads();
    if (t == 0) {
        double ent = she[0] + she[1] + she[2] + she[3];
        float  ssq = shs[0] + shs[1] + shs[2] + shs[3];
        out[(size_t)NTOK * DIM]     = 1.25f * ssq / (float)((size_t)NTOK * DIM);
        out[(size_t)NTOK * DIM + 1] = expf((float)(-ent));
    }
}

// ---------------------------------------------------------------------------
extern "C" void kernel_launch(void* const* d_in, const int* in_sizes, int n_in,
                              void* d_out, int out_size, void* d_ws, size_t ws_size,
                              hipStream_t stream) {
    const float* X = (const float*)d_in[0];   // [32,256,256] fp32
    const float* C = (const float*)d_in[1];   // [8192,256]   fp32
    float* out = (float*)d_out;

    char* ws = (char*)d_ws;
    size_t o = 0;
    _Float16* Xh = (_Float16*)(ws + o); o += (size_t)NTOK * DIM * 2;
    _Float16* Ch = (_Float16*)(ws + o); o += (size_t)NEMB * DIM * 2;
    float* cnorm = (float*)(ws + o); o += (size_t)NEMB * 4;
    float* xnorm = (float*)(ws + o); o += (size_t)NTOK * 4;
    unsigned long long* keys = (unsigned long long*)(ws + o); o += (size_t)NTOK * 8;
    int* counts  = (int*)(ws + o);   o += (size_t)NEMB * 4;
    int* done    = (int*)(ws + o);   o += 64 * 4;
    float* psum  = (float*)(ws + o);

    convert_kernel<<<dim3(NTOK * DIM / 4 / 256, 2), 256, 0, stream>>>(
        X, C, Xh, Ch, cnorm, xnorm, keys, counts, done);
    mfma_argmin_kernel<<<dim3(NTOK / 128, NEMB / 128), 256, 0, stream>>>(
        Xh, Ch, cnorm, keys, C, xnorm, counts, out, psum, done);
    finalize_kernel<<<1, 256, 0, stream>>>(counts, psum, out);
}

// Round 12
// 132.005 us; speedup vs baseline: 1.1499x; 1.1499x over previous
//
#include <hip/hip_runtime.h>
#include <math.h>

#define NTOK 8192
#define NEMB 8192
#define DIM  256

typedef _Float16 f16x8 __attribute__((ext_vector_type(8)));   // 4 VGPRs
typedef _Float16 f16x4 __attribute__((ext_vector_type(4)));
typedef float    f32x4 __attribute__((ext_vector_type(4)));

// ---------------------------------------------------------------------------
// Kernel A: cast X and C to fp16 (RNE); fused exact fp32 ||c||^2 and ||x||^2
// (each wave covers exactly one 256-elem row). C-branch blocks x<8 zero
// counts; X-branch blocks x<8 init keys to u64-max.
__global__ __launch_bounds__(256) void convert_kernel(
        const float* __restrict__ X, const float* __restrict__ C,
        _Float16* __restrict__ Xh, _Float16* __restrict__ Ch,
        float* __restrict__ cnorm, float* __restrict__ xnorm,
        unsigned long long* __restrict__ keys, int* __restrict__ counts) {
    const bool isC = (blockIdx.y != 0);
    if (isC && blockIdx.x < 8) {
        ((int4*)counts)[blockIdx.x * 256 + threadIdx.x] = make_int4(0, 0, 0, 0);
    }
    if (!isC && blockIdx.x < 8) {
        int4 ff = make_int4(-1, -1, -1, -1);
        ((int4*)keys)[blockIdx.x * 512 + threadIdx.x * 2]     = ff;
        ((int4*)keys)[blockIdx.x * 512 + threadIdx.x * 2 + 1] = ff;
    }
    const float* src = isC ? C : X;
    _Float16* dst = isC ? Ch : Xh;
    size_t t = (size_t)blockIdx.x * 256 + threadIdx.x;   // one float4 per thread
    float4 x = *(const float4*)&src[t * 4];
    f16x4 h;
    h[0] = (_Float16)x.x; h[1] = (_Float16)x.y;
    h[2] = (_Float16)x.z; h[3] = (_Float16)x.w;
    *(f16x4*)&dst[t * 4] = h;
    float s = x.x * x.x + x.y * x.y + x.z * x.z + x.w * x.w;
    #pragma unroll
    for (int off = 32; off >= 1; off >>= 1) s += __shfl_xor(s, off);
    if ((threadIdx.x & 63) == 0) {
        if (isC) cnorm[t >> 6] = s; else xnorm[t >> 6] = s;
    }
}

// ---------------------------------------------------------------------------
// K32-chunk staging: one 128x32 fp16 tile = 512 granules of 16B, 4 per row.
// Swizzle s(row) = (row + (row>>2)) & 3 keeps frag ds_read_b128 at 2-way
// (free): bank-quad (4r + (g ^ s(r))) mod 8 hits each quad exactly twice
// across the 16 rows of a frag read. Staging stays lane-contiguous in LDS
// (global side is un-swizzled instead).
__device__ __forceinline__ int swz(int row) { return (row + (row >> 2)) & 3; }

__device__ __forceinline__ void stage_pair32(
        const _Float16* __restrict__ Ag, const _Float16* __restrict__ Bg,
        _Float16* pair, int t) {
    #pragma unroll
    for (int c = 0; c < 2; ++c) {
        int gr  = c * 256 + t;                   // granule 0..511
        int row = gr >> 2;
        int kg  = (gr & 3) ^ swz(row);           // un-swizzle for global
        __builtin_amdgcn_global_load_lds(
            (const __attribute__((address_space(1))) void*)(Ag + (size_t)row * DIM + kg * 8),
            (__attribute__((address_space(3))) void*)(pair + (size_t)gr * 8), 16, 0, 0);
        __builtin_amdgcn_global_load_lds(
            (const __attribute__((address_space(1))) void*)(Bg + (size_t)row * DIM + kg * 8),
            (__attribute__((address_space(3))) void*)(pair + 4096 + (size_t)gr * 8), 16, 0, 0);
    }
}

__device__ __forceinline__ void compute_pair32(
        const _Float16* pair, f32x4 (&acc)[4][4],
        int wm, int wn, int lrow, int g) {
    const _Float16* Abase = pair;
    const _Float16* Bbase = pair + 4096;
    f16x8 af[4], bf_[4];
    #pragma unroll
    for (int tm = 0; tm < 4; ++tm) {
        int row = wm + tm * 16 + lrow;
        af[tm] = *(const f16x8*)&Abase[(row * 4 + (g ^ swz(row))) * 8];
    }
    #pragma unroll
    for (int tn = 0; tn < 4; ++tn) {
        int row = wn + tn * 16 + lrow;
        bf_[tn] = *(const f16x8*)&Bbase[(row * 4 + (g ^ swz(row))) * 8];
    }
    #pragma unroll
    for (int tm = 0; tm < 4; ++tm)
        #pragma unroll
        for (int tn = 0; tn < 4; ++tn)
            acc[tm][tn] = __builtin_amdgcn_mfma_f32_16x16x32_f16(
                af[tm], bf_[tn], acc[tm][tn], 0, 0, 0);
}

// ---------------------------------------------------------------------------
// Kernel B: fp16 distance GEMM (K=256, fp32 accum), A=codes (argmin over C/D
// rows), single-barrier double-buffered K32 staging. LDS 32 KB -> 4 blocks/CU
// (vs 2 at 64 KB): doubles the waves available to hide the barrier-drain
// latency that bounds the 64KB version (MfmaUtil 24.5% at 2 blk/CU).
// Epilogue: packed u64 key = bits(d+64)<<32 | code via atomicMin
// (order-isomorphic, tie -> lower code, order-independent => replay-safe).
__global__ __launch_bounds__(256) void mfma_argmin_kernel(
        const _Float16* __restrict__ Xh, const _Float16* __restrict__ Ch,
        const float* __restrict__ cnorm,
        unsigned long long* __restrict__ keys) {
    __shared__ __align__(16) _Float16 lds[16384];   // 32 KB: pair0, pair1

    const int t = threadIdx.x;
    const int wid = t >> 6, lane = t & 63;
    const int tb0 = blockIdx.x * 128;   // token block
    const int cb0 = blockIdx.y * 128;   // code block
    const int wm = (wid >> 1) * 64;     // wave's code offset
    const int wn = (wid & 1) * 64;      // wave's token offset
    const int lrow = lane & 15;
    const int g = lane >> 4;            // quad

    // preload cnorm into registers (uniform per quad -> broadcast loads;
    // overlaps with the K-loop, removes the old LDS round-trip + barrier)
    float cn[16];
    #pragma unroll
    for (int tm = 0; tm < 4; ++tm)
        #pragma unroll
        for (int reg = 0; reg < 4; ++reg)
            cn[tm * 4 + reg] = cnorm[cb0 + wm + tm * 16 + g * 4 + reg];

    f32x4 acc[4][4];                    // [tm=codes][tn=tokens]
    #pragma unroll
    for (int a = 0; a < 4; ++a)
        #pragma unroll
        for (int b = 0; b < 4; ++b) acc[a][b] = (f32x4)0.0f;

    const _Float16* Ag = Ch + (size_t)cb0 * DIM;   // codes
    const _Float16* Bg = Xh + (size_t)tb0 * DIM;   // tokens

    stage_pair32(Ag, Bg, lds, t);                  // phase 0 -> pair0
    __syncthreads();
    #pragma unroll
    for (int p = 0; p < 8; ++p) {
        _Float16* cur = lds + (p & 1) * 8192;
        if (p < 7) {
            _Float16* nxt = lds + ((p + 1) & 1) * 8192;
            stage_pair32(Ag + (p + 1) * 32, Bg + (p + 1) * 32, nxt, t);
        }
        compute_pair32(cur, acc, wm, wn, lrow, g);
        __syncthreads();
    }

    // ---- epilogue: d = ||c||^2 - 2 c.x ; argmin over this block's 128 codes
    float* cmb_v = (float*)lds;                    // [128][2]
    int*   cmb_i = (int*)((float*)lds + 256);      // [128][2]

    #pragma unroll
    for (int tn = 0; tn < 4; ++tn) {
        float bv = 1e30f; int bi = 0x7fffffff;
        #pragma unroll
        for (int tm = 0; tm < 4; ++tm) {
            #pragma unroll
            for (int reg = 0; reg < 4; ++reg) {
                float d = fmaf(-2.0f, acc[tm][tn][reg], cn[tm * 4 + reg]);
                int code = cb0 + wm + tm * 16 + g * 4 + reg;  // ascending -> strict <
                if (d < bv) { bv = d; bi = code; }
            }
        }
        #pragma unroll
        for (int off = 16; off <= 32; off <<= 1) {  // reduce over the 4 quads
            float ov = __shfl_xor(bv, off);
            int   oi = __shfl_xor(bi, off);
            if (ov < bv || (ov == bv && oi < bi)) { bv = ov; bi = oi; }
        }
        if (g == 0) {
            int tl = wn + tn * 16 + lrow;           // token-local 0..127
            cmb_v[tl * 2 + (wid >> 1)] = bv;
            cmb_i[tl * 2 + (wid >> 1)] = bi;
        }
    }
    __syncthreads();
    if (t < 128) {
        float v0 = cmb_v[t * 2], v1 = cmb_v[t * 2 + 1];
        int   i0 = cmb_i[t * 2], i1 = cmb_i[t * 2 + 1];
        bool tk = (v1 < v0) || (v1 == v0 && i1 < i0);
        float bv = tk ? v1 : v0;
        int   bi = tk ? i1 : i0;
        unsigned long long key =
            ((unsigned long long)__builtin_bit_cast(unsigned, bv + 64.0f) << 32)
            | (unsigned)bi;
        atomicMin(&keys[tb0 + t], key);
    }
}

// ---------------------------------------------------------------------------
// Kernel C: unpack keys -> idx + distance, histogram via device atomics,
// gather C rows -> out, per-block loss partial (||x-c||^2 = xnorm + d) to
// psum. 256 blocks x 32 tokens.
__global__ __launch_bounds__(256) void gather_kernel(
        const float* __restrict__ C, const unsigned long long* __restrict__ keys,
        const float* __restrict__ xnorm, int* __restrict__ counts,
        float* __restrict__ out, float* __restrict__ psum) {
    __shared__ int idx_lds[32];
    const int m0 = blockIdx.x * 32;
    const int t = threadIdx.x;
    if (t < 32) {
        unsigned long long k = keys[m0 + t];
        int bi  = (int)(unsigned)k;
        float d = __builtin_bit_cast(float, (unsigned)(k >> 32)) - 64.0f;
        idx_lds[t] = bi;
        atomicAdd(&counts[bi], 1);
        float lt = d + xnorm[m0 + t];               // ||x - c||^2 for this token
        #pragma unroll
        for (int off = 1; off < 32; off <<= 1) lt += __shfl_xor(lt, off);
        if (t == 0) psum[blockIdx.x] = lt;
    }
    __syncthreads();
    const int wid = t >> 6, lane = t & 63;
    #pragma unroll
    for (int r = 0; r < 8; ++r) {
        int token = m0 + wid * 8 + r;
        int e = idx_lds[wid * 8 + r];
        float4 q = *(const float4*)&C[(size_t)e * DIM + lane * 4];
        *(float4*)&out[(size_t)token * DIM + lane * 4] = q;
    }
}

// ---------------------------------------------------------------------------
// Kernel D: entropy over the 8192-bin histogram + loss. Single small block,
// plain loads (visibility via kernel boundary).
__global__ __launch_bounds__(256) void finalize_kernel(
        const int* __restrict__ counts, const float* __restrict__ psum,
        float* __restrict__ out) {
    const int t = threadIdx.x;
    double local = 0.0;
    #pragma unroll 1
    for (int e = t; e < NEMB; e += 256) {
        float p = (float)counts[e] * (1.0f / (float)NTOK);
        local += (double)(p * logf(p + 1e-10f));
    }
    float ls = psum[t];          // 256 threads, 256 partial sums
    #pragma unroll
    for (int off = 32; off >= 1; off >>= 1) {
        local += __shfl_xor(local, off);
        ls    += __shfl_xor(ls, off);
    }
    __shared__ double she[4];
    __shared__ float  shs[4];
    int lane = t & 63, wid = t >> 6;
    if (lane == 0) { she[wid] = local; shs[wid] = ls; }
    __syncthreads();
    if (t == 0) {
        double ent = she[0] + she[1] + she[2] + she[3];
        float  ssq = shs[0] + shs[1] + shs[2] + shs[3];
        out[(size_t)NTOK * DIM]     = 1.25f * ssq / (float)((size_t)NTOK * DIM);
        out[(size_t)NTOK * DIM + 1] = expf((float)(-ent));
    }
}

// ---------------------------------------------------------------------------
extern "C" void kernel_launch(void* const* d_in, const int* in_sizes, int n_in,
                              void* d_out, int out_size, void* d_ws, size_t ws_size,
                              hipStream_t stream) {
    const float* X = (const float*)d_in[0];   // [32,256,256] fp32
    const float* C = (const float*)d_in[1];   // [8192,256]   fp32
    float* out = (float*)d_out;

    char* ws = (char*)d_ws;
    size_t o = 0;
    _Float16* Xh = (_Float16*)(ws + o); o += (size_t)NTOK * DIM * 2;
    _Float16* Ch = (_Float16*)(ws + o); o += (size_t)NEMB * DIM * 2;
    float* cnorm = (float*)(ws + o); o += (size_t)NEMB * 4;
    float* xnorm = (float*)(ws + o); o += (size_t)NTOK * 4;
    unsigned long long* keys = (unsigned long long*)(ws + o); o += (size_t)NTOK * 8;
    int* counts  = (int*)(ws + o);   o += (size_t)NEMB * 4;
    float* psum  = (float*)(ws + o);

    convert_kernel<<<dim3(NTOK * DIM / 4 / 256, 2), 256, 0, stream>>>(
        X, C, Xh, Ch, cnorm, xnorm, keys, counts);
    mfma_argmin_kernel<<<dim3(NTOK / 128, NEMB / 128), 256, 0, stream>>>(
        Xh, Ch, cnorm, keys);
    gather_kernel<<<256, 256, 0, stream>>>(
        C, keys, xnorm, counts, out, psum);
    finalize_kernel<<<1, 256, 0, stream>>>(counts, psum, out);
}